// Round 12
// baseline (432.745 us; speedup 1.0000x reference)
//
#include <hip/hip_runtime.h>
#include <hip/hip_bf16.h>
#include <math.h>

#define B_ 4
#define N_ 1024
#define D_ 1024
#define H_ 16
#define HD_ 64
#define M_ (B_*N_)   // 4096

typedef __hip_bfloat16 bf16;
using floatx4 = __attribute__((ext_vector_type(4))) float;
using shortx8 = __attribute__((ext_vector_type(8))) short;

__device__ __forceinline__ float to_f(bf16 v) { return __bfloat162float(v); }
__device__ __forceinline__ float s2f(short v) {
    unsigned u = ((unsigned)(unsigned short)v) << 16;
    return __builtin_bit_cast(float, u);
}
__device__ __forceinline__ unsigned short bf_bits(float x) {
    bf16 h = __float2bfloat16(x);
    return *reinterpret_cast<unsigned short*>(&h);
}

#define GLOBAL_AS __attribute__((address_space(1)))
#define LDS_AS    __attribute__((address_space(3)))
__device__ __forceinline__ void load_lds16(const void* g, void* l) {
    __builtin_amdgcn_global_load_lds((const GLOBAL_AS unsigned int*)g,
                                     (LDS_AS unsigned int*)l, 16, 0, 0);
}

__device__ __forceinline__ void storec(float* p, float v) { *p = v; }
__device__ __forceinline__ void storec(bf16*  p, float v) { *p = __float2bfloat16(v); }

// ---------------------------------------------------------------------------
// MFMA GEMM: C = A @ W^T + bias (+resid).
// BMxBN block, 4 waves 2x2, 16x16x32 bf16 MFMA, 2-slot LDS dbuf.
// Round 2: XCD-chunked bid remap under GROUP_M=8 (FETCH -20%, kept).
// Round 4: XOR chunk swizzle -> SQ_LDS_BANK_CONFLICT == 0 (kept).
// Round 5: BK=64 on grid-capped dispatches (kept, -16us).
// Round 10: qkv BN=192/BK=64 -> grid 512 = exactly 2/CU, 3x MFMA/barrier
//   (kept, -6.4us). The density-at-2/CU mechanism is now applied everywhere
//   it divides; msg/ffn2 BN=64 stay (densifying drops them to 1/CU).
// Swizzle (zero-conflict): CH = BK/8 chunks of 16B per row.
//   BK=64: chunk c -> c ^ (r&7); BK=32: c -> c ^ ((r>>1)&3).
//   LDS dest LINEAR (global_load_lds), source chunk inverse-swizzled,
//   frag read applies same XOR (rule #21).
// SPLIT: A cols [0,K1) from A, [K1,K) from A2 (K1 % BK == 0 required).
// ---------------------------------------------------------------------------
template<typename TC, bool RESID, bool SPLIT, int BM, int BN, int BK>
__global__ __launch_bounds__(256)
void mgemm(const bf16* __restrict__ A, int lda,
           const bf16* __restrict__ A2, int lda2, int K1,
           const bf16* __restrict__ W, int ldw,
           const float* __restrict__ bias,
           const float* __restrict__ resid, int ldr,
           TC* __restrict__ C, int ldc,
           int M, int N, int K)
{
    constexpr int MT  = BM / 32;        // row 16-tiles per wave
    constexpr int NT  = BN / 32;        // col 16-tiles per wave
    constexpr int KH  = BK / 32;        // MFMA K-steps per tile
    constexpr int CH  = BK / 8;         // 16B chunks per row
    constexpr int ASZ = BM * BK;
    constexpr int BSZ = BN * BK;
    constexpr int APASS = (BM * CH) / 256;
    constexpr int BPASS = (BN * CH) / 256;
    __shared__ short lds[2 * (ASZ + BSZ)];

    int t = threadIdx.x;
    int lane = t & 63, quad = lane >> 4, l15 = lane & 15;
    int wave = t >> 6, wm = wave & 1, wn = wave >> 1;

    int gx = gridDim.x;
    int nwg = gx * gridDim.y;
    int p = blockIdx.y * gx + blockIdx.x;
    // XCD-chunked remap (bijective; guarded for nwg%8!=0)
    int bid;
    if (nwg & 7) bid = p;
    else         bid = (p & 7) * (nwg >> 3) + (p >> 3);
    // GROUP_M=8 swizzle: 8 consecutive bids share one W-col panel
    int seg = bid / (8 * gx);
    int rem = bid - seg * 8 * gx;
    int bx = rem >> 3;
    int by = seg * 8 + (rem & 7);
    int row0 = by * BM, col0 = bx * BN;

    const short* Ag  = (const short*)A;
    const short* A2g = (const short*)A2;
    const short* Wg  = (const short*)W;

    auto swz = [](int r, int c) -> int {
        if constexpr (CH == 4) return c ^ ((r >> 1) & 3);
        else                   return c ^ (r & 7);
    };

    auto stage = [&](int buf, int k0) {
        short* As = lds + buf * (ASZ + BSZ);
        short* Bs = As + ASZ;
        #pragma unroll
        for (int pass = 0; pass < APASS; ++pass) {
            int idx = pass * 256 + t;
            int r = idx / CH, c = idx % CH;
            int cs = swz(r, c) << 3;                   // inverse-swizzled src chunk
            int wub = (pass * 256 + (t & 192)) * 8;    // linear wave-uniform dest
            const short* asrc;
            if (SPLIT && k0 >= K1)
                asrc = A2g + (size_t)(row0 + r) * lda2 + (k0 - K1) + cs;
            else
                asrc = Ag + (size_t)(row0 + r) * lda + k0 + cs;
            load_lds16(asrc, &As[wub]);
        }
        #pragma unroll
        for (int pass = 0; pass < BPASS; ++pass) {
            int idx = pass * 256 + t;
            int r = idx / CH, c = idx % CH;
            int cs = swz(r, c) << 3;
            int wub = (pass * 256 + (t & 192)) * 8;
            load_lds16(Wg + (size_t)(col0 + r) * ldw + k0 + cs, &Bs[wub]);
        }
    };

    floatx4 acc[MT][NT];
    #pragma unroll
    for (int mt = 0; mt < MT; ++mt)
        #pragma unroll
        for (int nt = 0; nt < NT; ++nt)
            acc[mt][nt] = (floatx4){0.f, 0.f, 0.f, 0.f};

    stage(0, 0);
    int buf = 0;
    for (int k0 = 0; k0 < K; k0 += BK, buf ^= 1) {
        __syncthreads();   // drains this buf's staged loads; prev readers done

        // issue next tile's stage FIRST -- loads fly over the frag ds_reads
        // AND the MFMA cluster (T3 order).
        if (k0 + BK < K) stage(buf ^ 1, k0 + BK);

        const short* As = lds + buf * (ASZ + BSZ);
        const short* Bs = As + ASZ;
        shortx8 af[MT][KH], bfv[NT][KH];
        #pragma unroll
        for (int mt = 0; mt < MT; ++mt) {
            int ar = wm * (BM / 2) + mt * 16 + l15;
            #pragma unroll
            for (int kk = 0; kk < KH; ++kk)
                af[mt][kk] = *(const shortx8*)&As[ar * BK + (swz(ar, kk * 4 + quad) << 3)];
        }
        #pragma unroll
        for (int nt = 0; nt < NT; ++nt) {
            int br = wn * (BN / 2) + nt * 16 + l15;
            #pragma unroll
            for (int kk = 0; kk < KH; ++kk)
                bfv[nt][kk] = *(const shortx8*)&Bs[br * BK + (swz(br, kk * 4 + quad) << 3)];
        }
        #pragma unroll
        for (int kk = 0; kk < KH; ++kk)
            #pragma unroll
            for (int mt = 0; mt < MT; ++mt)
                #pragma unroll
                for (int nt = 0; nt < NT; ++nt)
                    acc[mt][nt] = __builtin_amdgcn_mfma_f32_16x16x32_bf16(
                        af[mt][kk], bfv[nt][kk], acc[mt][nt], 0, 0, 0);
    }

    #pragma unroll
    for (int mt = 0; mt < MT; ++mt) {
        #pragma unroll
        for (int nt = 0; nt < NT; ++nt) {
            int col = col0 + wn * (BN / 2) + nt * 16 + l15;
            float bv = bias[col];
            #pragma unroll
            for (int r = 0; r < 4; ++r) {
                int row = row0 + wm * (BM / 2) + mt * 16 + quad * 4 + r;
                float v = acc[mt][nt][r] + bv;
                if (RESID) v += resid[(size_t)row * ldr + col];
                storec(&C[(size_t)row * ldc + col], v);
            }
        }
    }
}

// fused fp32 -> bf16 convert for 5 tensors; each block handles 1024 elems
__global__ void f2b_all(const float* __restrict__ s0, bf16* __restrict__ d0,
                        const float* __restrict__ s1, bf16* __restrict__ d1,
                        const float* __restrict__ s2, bf16* __restrict__ d2,
                        const float* __restrict__ s3, bf16* __restrict__ d3,
                        const float* __restrict__ s4, bf16* __restrict__ d4)
{
    int blk = blockIdx.x;
    const float* s; bf16* d; int base;
    if      (blk < 4096)  { s = s0; d = d0; base = blk; }
    else if (blk < 7168)  { s = s1; d = d1; base = blk - 4096; }
    else if (blk < 8192)  { s = s2; d = d2; base = blk - 7168; }
    else if (blk < 12288) { s = s3; d = d3; base = blk - 8192; }
    else                  { s = s4; d = d4; base = blk - 12288; }
    int i = base * 1024 + threadIdx.x * 4;
    float4 v = *(const float4*)&s[i];
    d[i + 0] = __float2bfloat16(v.x);
    d[i + 1] = __float2bfloat16(v.y);
    d[i + 2] = __float2bfloat16(v.z);
    d[i + 3] = __float2bfloat16(v.w);
}

// ---------------------------------------------------------------------------
// rope_all: block = (n-tile 64, h, b). Reads qkv[b,n][h*192 + d*3 + c] once via
// an LDS tile, writes RoPE'd q,k in [B,H,N,64] and V transposed in [B,H,64,N].
// ---------------------------------------------------------------------------
#define RS 196
__global__ __launch_bounds__(256)
void rope_all(const bf16* __restrict__ qkv, const float* __restrict__ enc,
              bf16* __restrict__ q, bf16* __restrict__ k, bf16* __restrict__ vt)
{
    __shared__ short raw[64 * RS];
    int n0 = blockIdx.x * 64, h = blockIdx.y, b = blockIdx.z;
    int t = threadIdx.x;
    const short* qg = (const short*)qkv;

    {
        int row = t >> 2, off = (t & 3) * 48;
        const short* src = qg + ((size_t)(b * N_ + n0 + row)) * 3072 + h * 192 + off;
        uint4 u[3];
        u[0] = ((const uint4*)src)[0];
        u[1] = ((const uint4*)src)[1];
        u[2] = ((const uint4*)src)[2];
        uint4 u2[3];
        u2[0] = ((const uint4*)src)[3];
        u2[1] = ((const uint4*)src)[4];
        u2[2] = ((const uint4*)src)[5];
        uint2* dst = (uint2*)&raw[row * RS + off];
        const uint2* p = (const uint2*)u;
        #pragma unroll
        for (int i = 0; i < 6; ++i) dst[i] = p[i];
        const uint2* p2 = (const uint2*)u2;
        #pragma unroll
        for (int i = 0; i < 6; ++i) dst[6 + i] = p2[i];
    }
    __syncthreads();

    size_t bh = (size_t)(b * H_ + h);
    {
        int d = t & 63, g0 = t >> 6;
        int dp = d ^ 1;
        float sgn = (d & 1) ? 1.0f : -1.0f;
        #pragma unroll
        for (int i = 0; i < 16; ++i) {
            int nl = g0 + 4 * i;
            const short* r = &raw[nl * RS];
            float qv = s2f(r[3 * d]),  kv = s2f(r[3 * d + 1]);
            float qp = s2f(r[3 * dp]), kp = s2f(r[3 * dp + 1]);
            size_t ei = ((size_t)(b * N_ + n0 + nl)) * HD_ + d;
            float c = enc[ei];
            float s = enc[(size_t)B_ * N_ * HD_ + ei];
            size_t o = (bh * N_ + n0 + nl) * HD_ + d;
            q[o] = __float2bfloat16(qv * c + sgn * qp * s);
            k[o] = __float2bfloat16(kv * c + sgn * kp * s);
        }
    }
    {
        int nl = t & 63, g0 = t >> 6;
        #pragma unroll
        for (int i = 0; i < 16; ++i) {
            int dt = g0 + 4 * i;
            vt[(bh * HD_ + dt) * N_ + n0 + nl] =
                *reinterpret_cast<bf16*>(&raw[nl * RS + 3 * dt + 2]);
        }
    }
}

// ---------------------------------------------------------------------------
// MFMA flash attention v8. Round 11: T15 double-pipeline. Keep the PREVIOUS
// tile's scores STp in registers; each iteration issues QK^T(tile it+1)
// (async MFMA) then runs exp+PV of tile it -- the exp VALU has no dependency
// on the in-flight MFMAs, so MFMA and VALU pipes overlap within each wave
// (guide T15: +7-11% attn measured). 2 barriers/iter (r8 showed barrier
// count neutral). Buffer safety: iter it writes bufs[(it+1)&1] after the top
// barrier (its prior readers -- QK^T iter it-1, PV iter it-1 -- are before
// it); this iter reads Ks[(it+1)&1] (after 2nd barrier) and Vs[it&1].
// QBLK=128, LDS 54KB, 2 blocks/CU.
// ---------------------------------------------------------------------------
__global__ __launch_bounds__(256, 2)
void fattn(const bf16* __restrict__ q, const bf16* __restrict__ k,
           const bf16* __restrict__ vt, bf16* __restrict__ ctx)
{
    const int i0 = blockIdx.x * 128;
    const int h = blockIdx.y, b = blockIdx.z;
    const int t = threadIdx.x;
    const int lane = t & 63;
    const int w = t >> 6;
    const int quad = lane >> 4, l15 = lane & 15;

    __shared__ alignas(16) short Ks[2][64 * 72];   // [buf][key][d]
    __shared__ alignas(16) short Vs[2][64 * 72];   // [buf][d][key]
    __shared__ alignas(16) short Ps[128 * 72];     // [q-row][key]

    const size_t bh = (size_t)(b * H_ + h) * N_;
    const size_t bhv = (size_t)(b * H_ + h) * HD_;
    const short* qg = (const short*)q;
    const short* kg = (const short*)k;
    const short* vg = (const short*)vt;

    // Q fragments (B-operand: n = q-row = l15, k = quad*8+j)
    shortx8 qf[2][2];
    #pragma unroll
    for (int rt = 0; rt < 2; ++rt) {
        const short* qrow = qg + (bh + i0 + w * 32 + rt * 16 + l15) * HD_;
        qf[rt][0] = *(const shortx8*)(qrow + quad * 8);
        qf[rt][1] = *(const shortx8*)(qrow + 32 + quad * 8);
    }

    floatx4 O[2][4];
    #pragma unroll
    for (int rt = 0; rt < 2; ++rt)
        #pragma unroll
        for (int dt = 0; dt < 4; ++dt) O[rt][dt] = (floatx4){0.f, 0.f, 0.f, 0.f};
    // per-lane partial row sums: q-row = w*32 + rt*16 + l15, keys {16kt + quad*4 + r}
    float lsum[2] = {0.f, 0.f};

    const int srow = t >> 2, soff = (t & 3) * 16;
    const short* kst = kg + (bh + srow) * HD_ + soff;     // + j0*HD_ per tile
    const short* vst = vg + (bhv + srow) * N_ + soff;     // + j0 per tile

    // prologue: tile 0 -> bufs[0]
    {
        uint4 a0 = ((const uint4*)kst)[0];
        uint4 a1 = ((const uint4*)kst)[1];
        uint4 b0 = ((const uint4*)vst)[0];
        uint4 b1 = ((const uint4*)vst)[1];
        *(uint4*)&Ks[0][srow * 72 + soff]     = a0;
        *(uint4*)&Ks[0][srow * 72 + soff + 8] = a1;
        *(uint4*)&Vs[0][srow * 72 + soff]     = b0;
        *(uint4*)&Vs[0][srow * 72 + soff + 8] = b1;
    }
    __syncthreads();

    // tile 1 -> regs (T14 issue-early)
    uint4 ka0, ka1, va0, va1;
    {
        const short* kn = kst + (size_t)64 * HD_;
        const short* vn = vst + 64;
        ka0 = ((const uint4*)kn)[0];
        ka1 = ((const uint4*)kn)[1];
        va0 = ((const uint4*)vn)[0];
        va1 = ((const uint4*)vn)[1];
    }

    // S^T = K Q^T : A = K-frag (m=key), B = Q-frag (n=q-row)
    // C-layout: col(l15) = q-row, row(quad*4+r) = key
    auto qkt = [&](const short* Kbuf, floatx4 ST[4][2]) {
        __builtin_amdgcn_s_setprio(1);
        #pragma unroll
        for (int kt = 0; kt < 4; ++kt) {
            shortx8 a0 = *(const shortx8*)&Kbuf[(kt * 16 + l15) * 72 + quad * 8];
            shortx8 a1 = *(const shortx8*)&Kbuf[(kt * 16 + l15) * 72 + 32 + quad * 8];
            #pragma unroll
            for (int rt = 0; rt < 2; ++rt) {
                floatx4 c = (floatx4){0.f, 0.f, 0.f, 0.f};
                c = __builtin_amdgcn_mfma_f32_16x16x32_bf16(a0, qf[rt][0], c, 0, 0, 0);
                c = __builtin_amdgcn_mfma_f32_16x16x32_bf16(a1, qf[rt][1], c, 0, 0, 0);
                ST[kt][rt] = c;
            }
        }
        __builtin_amdgcn_s_setprio(0);
    };

    // exp + pack + Ps round-trip + PV for one tile (Vs[cur])
    auto exppv = [&](int cur, floatx4 ST[4][2]) {
        #pragma unroll
        for (int kt = 0; kt < 4; ++kt)
            #pragma unroll
            for (int rt = 0; rt < 2; ++rt) {
                unsigned short pk[4];
                #pragma unroll
                for (int r = 0; r < 4; ++r) {
                    float e = __expf(ST[kt][rt][r] * 0.125f);
                    lsum[rt] += e;
                    pk[r] = bf_bits(e);
                }
                *(uint2*)&Ps[(w * 32 + rt * 16 + l15) * 72 + kt * 16 + quad * 4] =
                    *(const uint2*)pk;
            }
        // PV (same-wave Ps write->read; per-wave LDS ordering)
        shortx8 pa[2][2];
        #pragma unroll
        for (int rt = 0; rt < 2; ++rt) {
            pa[rt][0] = *(const shortx8*)&Ps[(w * 32 + rt * 16 + l15) * 72 + quad * 8];
            pa[rt][1] = *(const shortx8*)&Ps[(w * 32 + rt * 16 + l15) * 72 + 32 + quad * 8];
        }
        __builtin_amdgcn_s_setprio(1);
        #pragma unroll
        for (int dt = 0; dt < 4; ++dt) {
            shortx8 vb0 = *(const shortx8*)&Vs[cur][(dt * 16 + l15) * 72 + quad * 8];
            shortx8 vb1 = *(const shortx8*)&Vs[cur][(dt * 16 + l15) * 72 + 32 + quad * 8];
            #pragma unroll
            for (int rt = 0; rt < 2; ++rt) {
                O[rt][dt] = __builtin_amdgcn_mfma_f32_16x16x32_bf16(pa[rt][0], vb0, O[rt][dt], 0, 0, 0);
                O[rt][dt] = __builtin_amdgcn_mfma_f32_16x16x32_bf16(pa[rt][1], vb1, O[rt][dt], 0, 0, 0);
            }
        }
        __builtin_amdgcn_s_setprio(0);
    };

    floatx4 STp[4][2];
    qkt(Ks[0], STp);   // tile 0 scores

    #pragma unroll 2
    for (int it = 0; it < 15; ++it) {
        const int nb = (it + 1) & 1;
        __syncthreads();   // prev iter's PV(Vs[nb]) + QK^T(Ks[nb]) readers done

        // write tile it+1 staged regs -> bufs[nb]
        *(uint4*)&Ks[nb][srow * 72 + soff]     = ka0;
        *(uint4*)&Ks[nb][srow * 72 + soff + 8] = ka1;
        *(uint4*)&Vs[nb][srow * 72 + soff]     = va0;
        *(uint4*)&Vs[nb][srow * 72 + soff + 8] = va1;

        // issue tile it+2 loads (T14): fly over the whole compute phase
        if (it + 2 < 16) {
            const short* kn = kst + (size_t)((it + 2) * 64) * HD_;
            const short* vn = vst + (it + 2) * 64;
            ka0 = ((const uint4*)kn)[0];
            ka1 = ((const uint4*)kn)[1];
            va0 = ((const uint4*)vn)[0];
            va1 = ((const uint4*)vn)[1];
        }
        __syncthreads();   // tile it+1 visible to all waves

        floatx4 STn[4][2];
        qkt(Ks[nb], STn);      // async MFMA; results consumed NEXT iteration
        exppv(it & 1, STp);    // VALU exp + PV(tile it) overlap the QK^T MFMAs

        #pragma unroll
        for (int kt = 0; kt < 4; ++kt)
            #pragma unroll
            for (int rt = 0; rt < 2; ++rt)
                STp[kt][rt] = STn[kt][rt];
    }
    // final tile 15 (scores already in STp; buf = 15&1 = 1)
    exppv(1, STp);

    // epilogue: complete row sums (reduce across quads -> full sum at q-row=l15),
    // redistribute to O's row indexing (q-row = quad*4 + r) via shfl, store.
    #pragma unroll
    for (int rt = 0; rt < 2; ++rt) {
        float rs = lsum[rt];
        rs += __shfl_xor(rs, 16);
        rs += __shfl_xor(rs, 32);
        #pragma unroll
        for (int r = 0; r < 4; ++r) {
            float inv = 1.0f / __shfl(rs, quad * 4 + r);
            int row = i0 + w * 32 + rt * 16 + quad * 4 + r;
            #pragma unroll
            for (int dt = 0; dt < 4; ++dt)
                ctx[((size_t)(b * N_ + row)) * D_ + h * HD_ + dt * 16 + l15] =
                    __float2bfloat16(O[rt][dt][r] * inv);
        }
    }
}

// LayerNorm over 2048 cols + exact GELU, in place on bf16. One block per row.
// Vectorized b128 loads/stores (8 bf16/thread) + shfl-based reduction.
__global__ void ln_gelu(bf16* __restrict__ hbuf, const float* __restrict__ g,
                        const float* __restrict__ beta)
{
    int row = blockIdx.x;
    int t = threadIdx.x;
    short* hr = (short*)hbuf + (size_t)row * 2048;

    shortx8 v = *(const shortx8*)&hr[t * 8];
    float vals[8];
    float s = 0.f, s2 = 0.f;
    #pragma unroll
    for (int l = 0; l < 8; ++l) {
        float x = s2f(v[l]);
        vals[l] = x; s += x; s2 += x * x;
    }
    // wave reduce (64 lanes), then 4 wave partials via LDS
    #pragma unroll
    for (int off = 32; off >= 1; off >>= 1) {
        s  += __shfl_xor(s,  off);
        s2 += __shfl_xor(s2, off);
    }
    __shared__ float ws_[4], ws2_[4];
    if ((t & 63) == 0) { ws_[t >> 6] = s; ws2_[t >> 6] = s2; }
    __syncthreads();
    float S  = ws_[0] + ws_[1] + ws_[2] + ws_[3];
    float S2 = ws2_[0] + ws2_[1] + ws2_[2] + ws2_[3];

    float mu  = S * (1.0f / 2048.0f);
    float var = S2 * (1.0f / 2048.0f) - mu * mu;
    float rstd = rsqrtf(var + 1e-5f);

    float4 g0 = *(const float4*)&g[t * 8];
    float4 g1 = *(const float4*)&g[t * 8 + 4];
    float4 b0 = *(const float4*)&beta[t * 8];
    float4 b1 = *(const float4*)&beta[t * 8 + 4];
    float gv[8] = {g0.x, g0.y, g0.z, g0.w, g1.x, g1.y, g1.z, g1.w};
    float bv[8] = {b0.x, b0.y, b0.z, b0.w, b1.x, b1.y, b1.z, b1.w};

    shortx8 o;
    #pragma unroll
    for (int l = 0; l < 8; ++l) {
        float xn = (vals[l] - mu) * rstd * gv[l] + bv[l];
        float ge = 0.5f * xn * (1.0f + erff(xn * 0.70710678118654752f));
        o[l] = (short)bf_bits(ge);
    }
    *(shortx8*)&hr[t * 8] = o;
}

extern "C" void kernel_launch(void* const* d_in, const int* in_sizes, int n_in,
                              void* d_out, int out_size, void* d_ws, size_t ws_size,
                              hipStream_t stream)
{
    const float* x      = (const float*)d_in[0];
    const float* enc    = (const float*)d_in[1];
    const float* Wqkv_w = (const float*)d_in[2];
    const float* Wqkv_b = (const float*)d_in[3];
    const float* out_w  = (const float*)d_in[4];
    const float* out_b  = (const float*)d_in[5];
    const float* ffn1_w = (const float*)d_in[6];
    const float* ffn1_b = (const float*)d_in[7];
    const float* ln_g   = (const float*)d_in[8];
    const float* ln_b   = (const float*)d_in[9];
    const float* ffn2_w = (const float*)d_in[10];
    const float* ffn2_b = (const float*)d_in[11];
    float* out = (float*)d_out;

    float* ws = (float*)d_ws;
    bf16* qkv16 = (bf16*)ws;
    bf16* ctx16 = (bf16*)ws;
    bf16* h16   = (bf16*)(ws + 2097152);
    bf16* q16   = (bf16*)(ws + 6291456);
    bf16* k16   = q16 + 2097152;
    bf16* vt16  = k16 + 2097152;
    bf16* msg16 = (bf16*)(ws + 6291456);    // overlays q16 after fattn
    bf16* x16   = (bf16*)(ws + 12582912);
    bf16* wq16  = (bf16*)(ws + 14680064);
    bf16* wo16  = wq16 + 3145728;
    bf16* wf1   = wo16 + 1048576;
    bf16* wf2   = wf1 + 4194304;

    // 0. fused converts (x, Wqkv, out_w, ffn1_w, ffn2_w)
    f2b_all<<<14336, 256, 0, stream>>>(x, x16, Wqkv_w, wq16, out_w, wo16,
                                       ffn1_w, wf1, ffn2_w, wf2);

    // 1. qkv = x @ Wqkv^T + b  [4096, 3072] bf16
    //    BN=192/BK=64: grid 16x32 = 512 = exactly 2 blocks/CU (LDS 80KB),
    //    no tail, 3x MFMA per barrier vs the old BK=32 config.
    dim3 g1(3072 / 192, 4096 / 128);
    mgemm<bf16, false, false, 128, 192, 64><<<g1, 256, 0, stream>>>(
        x16, 1024, nullptr, 0, 0, wq16, 1024, Wqkv_b, nullptr, 0,
        qkv16, 3072, 4096, 3072, 1024);

    // 2. RoPE + split + V-transpose
    dim3 gr(16, 16, 4);
    rope_all<<<gr, 256, 0, stream>>>(qkv16, enc, q16, k16, vt16);

    // 3. MFMA flash attention -> ctx bf16 [4096, 1024] (grid 512, QBLK=128)
    dim3 ga(N_ / 128, H_, B_);
    fattn<<<ga, 256, 0, stream>>>(q16, k16, vt16, ctx16);

    // 4. message = ctx @ out_w^T + out_b -> msg16 (grid 512 = 2/CU: BK=64)
    dim3 g2(1024 / 64, 4096 / 128);
    mgemm<bf16, false, false, 128, 64, 64><<<g2, 256, 0, stream>>>(
        ctx16, 1024, nullptr, 0, 0, wo16, 1024, out_b, nullptr, 0,
        msg16, 1024, 4096, 1024, 1024);

    // 5. h = [x | message] @ ffn1_w^T + ffn1_b  (grid 512 = 2/CU: BK=64)
    dim3 g3(2048 / 128, 4096 / 128);
    mgemm<bf16, false, true, 128, 128, 64><<<g3, 256, 0, stream>>>(
        x16, 1024, msg16, 1024, 1024, wf1, 2048, ffn1_b, nullptr, 0,
        h16, 2048, 4096, 2048, 2048);

    // 6. LayerNorm + exact GELU in place (bf16)
    ln_gelu<<<4096, 256, 0, stream>>>(h16, ln_g, ln_b);

    // 7. out = x + h @ ffn2_w^T + ffn2_b  (grid 512 = 2/CU: BK=64)
    dim3 g4(1024 / 64, 4096 / 128);
    mgemm<float, true, false, 128, 64, 64><<<g4, 256, 0, stream>>>(
        h16, 2048, nullptr, 0, 0, wf2, 2048, ffn2_b, x, 1024,
        out, 1024, 4096, 1024, 2048);
}

// Round 13
// 263.130 us; speedup vs baseline: 1.6446x; 1.6446x over previous
//
#include <hip/hip_runtime.h>
#include <hip/hip_bf16.h>
#include <math.h>

#define B_ 4
#define N_ 1024
#define D_ 1024
#define H_ 16
#define HD_ 64
#define M_ (B_*N_)   // 4096

typedef __hip_bfloat16 bf16;
using floatx4 = __attribute__((ext_vector_type(4))) float;
using shortx8 = __attribute__((ext_vector_type(8))) short;

__device__ __forceinline__ float to_f(bf16 v) { return __bfloat162float(v); }
__device__ __forceinline__ float s2f(short v) {
    unsigned u = ((unsigned)(unsigned short)v) << 16;
    return __builtin_bit_cast(float, u);
}
__device__ __forceinline__ unsigned short bf_bits(float x) {
    bf16 h = __float2bfloat16(x);
    return *reinterpret_cast<unsigned short*>(&h);
}

#define GLOBAL_AS __attribute__((address_space(1)))
#define LDS_AS    __attribute__((address_space(3)))
__device__ __forceinline__ void load_lds16(const void* g, void* l) {
    __builtin_amdgcn_global_load_lds((const GLOBAL_AS unsigned int*)g,
                                     (LDS_AS unsigned int*)l, 16, 0, 0);
}

__device__ __forceinline__ void storec(float* p, float v) { *p = v; }
__device__ __forceinline__ void storec(bf16*  p, float v) { *p = __float2bfloat16(v); }

// ---------------------------------------------------------------------------
// MFMA GEMM: C = A @ W^T + bias (+resid).
// BMxBN block, 4 waves 2x2, 16x16x32 bf16 MFMA, 2-slot LDS dbuf.
// Round 2: XCD-chunked bid remap under GROUP_M=8 (FETCH -20%, kept).
// Round 4: XOR chunk swizzle -> SQ_LDS_BANK_CONFLICT == 0 (kept).
// Round 5: BK=64 on grid-capped dispatches (kept, -16us).
// Round 10: qkv BN=192/BK=64 -> grid 512 = exactly 2/CU, 3x MFMA/barrier
//   (kept, -6.4us).
// Round 12: fattn T15 double-pipeline REVERTED -- VGPR spill (128-cap,
//   FETCH 150MB of scratch traffic, fattn 30->167us). T15's VGPR
//   prerequisite is structurally unmet in the 4-wave Ps-round-trip design.
// Swizzle (zero-conflict): CH = BK/8 chunks of 16B per row.
//   BK=64: chunk c -> c ^ (r&7); BK=32: c -> c ^ ((r>>1)&3).
//   LDS dest LINEAR (global_load_lds), source chunk inverse-swizzled,
//   frag read applies same XOR (rule #21).
// SPLIT: A cols [0,K1) from A, [K1,K) from A2 (K1 % BK == 0 required).
// ---------------------------------------------------------------------------
template<typename TC, bool RESID, bool SPLIT, int BM, int BN, int BK>
__global__ __launch_bounds__(256)
void mgemm(const bf16* __restrict__ A, int lda,
           const bf16* __restrict__ A2, int lda2, int K1,
           const bf16* __restrict__ W, int ldw,
           const float* __restrict__ bias,
           const float* __restrict__ resid, int ldr,
           TC* __restrict__ C, int ldc,
           int M, int N, int K)
{
    constexpr int MT  = BM / 32;        // row 16-tiles per wave
    constexpr int NT  = BN / 32;        // col 16-tiles per wave
    constexpr int KH  = BK / 32;        // MFMA K-steps per tile
    constexpr int CH  = BK / 8;         // 16B chunks per row
    constexpr int ASZ = BM * BK;
    constexpr int BSZ = BN * BK;
    constexpr int APASS = (BM * CH) / 256;
    constexpr int BPASS = (BN * CH) / 256;
    __shared__ short lds[2 * (ASZ + BSZ)];

    int t = threadIdx.x;
    int lane = t & 63, quad = lane >> 4, l15 = lane & 15;
    int wave = t >> 6, wm = wave & 1, wn = wave >> 1;

    int gx = gridDim.x;
    int nwg = gx * gridDim.y;
    int p = blockIdx.y * gx + blockIdx.x;
    // XCD-chunked remap (bijective; guarded for nwg%8!=0)
    int bid;
    if (nwg & 7) bid = p;
    else         bid = (p & 7) * (nwg >> 3) + (p >> 3);
    // GROUP_M=8 swizzle: 8 consecutive bids share one W-col panel
    int seg = bid / (8 * gx);
    int rem = bid - seg * 8 * gx;
    int bx = rem >> 3;
    int by = seg * 8 + (rem & 7);
    int row0 = by * BM, col0 = bx * BN;

    const short* Ag  = (const short*)A;
    const short* A2g = (const short*)A2;
    const short* Wg  = (const short*)W;

    auto swz = [](int r, int c) -> int {
        if constexpr (CH == 4) return c ^ ((r >> 1) & 3);
        else                   return c ^ (r & 7);
    };

    auto stage = [&](int buf, int k0) {
        short* As = lds + buf * (ASZ + BSZ);
        short* Bs = As + ASZ;
        #pragma unroll
        for (int pass = 0; pass < APASS; ++pass) {
            int idx = pass * 256 + t;
            int r = idx / CH, c = idx % CH;
            int cs = swz(r, c) << 3;                   // inverse-swizzled src chunk
            int wub = (pass * 256 + (t & 192)) * 8;    // linear wave-uniform dest
            const short* asrc;
            if (SPLIT && k0 >= K1)
                asrc = A2g + (size_t)(row0 + r) * lda2 + (k0 - K1) + cs;
            else
                asrc = Ag + (size_t)(row0 + r) * lda + k0 + cs;
            load_lds16(asrc, &As[wub]);
        }
        #pragma unroll
        for (int pass = 0; pass < BPASS; ++pass) {
            int idx = pass * 256 + t;
            int r = idx / CH, c = idx % CH;
            int cs = swz(r, c) << 3;
            int wub = (pass * 256 + (t & 192)) * 8;
            load_lds16(Wg + (size_t)(col0 + r) * ldw + k0 + cs, &Bs[wub]);
        }
    };

    floatx4 acc[MT][NT];
    #pragma unroll
    for (int mt = 0; mt < MT; ++mt)
        #pragma unroll
        for (int nt = 0; nt < NT; ++nt)
            acc[mt][nt] = (floatx4){0.f, 0.f, 0.f, 0.f};

    stage(0, 0);
    int buf = 0;
    for (int k0 = 0; k0 < K; k0 += BK, buf ^= 1) {
        __syncthreads();   // drains this buf's staged loads; prev readers done

        // issue next tile's stage FIRST -- loads fly over the frag ds_reads
        // AND the MFMA cluster (T3 order).
        if (k0 + BK < K) stage(buf ^ 1, k0 + BK);

        const short* As = lds + buf * (ASZ + BSZ);
        const short* Bs = As + ASZ;
        shortx8 af[MT][KH], bfv[NT][KH];
        #pragma unroll
        for (int mt = 0; mt < MT; ++mt) {
            int ar = wm * (BM / 2) + mt * 16 + l15;
            #pragma unroll
            for (int kk = 0; kk < KH; ++kk)
                af[mt][kk] = *(const shortx8*)&As[ar * BK + (swz(ar, kk * 4 + quad) << 3)];
        }
        #pragma unroll
        for (int nt = 0; nt < NT; ++nt) {
            int br = wn * (BN / 2) + nt * 16 + l15;
            #pragma unroll
            for (int kk = 0; kk < KH; ++kk)
                bfv[nt][kk] = *(const shortx8*)&Bs[br * BK + (swz(br, kk * 4 + quad) << 3)];
        }
        #pragma unroll
        for (int kk = 0; kk < KH; ++kk)
            #pragma unroll
            for (int mt = 0; mt < MT; ++mt)
                #pragma unroll
                for (int nt = 0; nt < NT; ++nt)
                    acc[mt][nt] = __builtin_amdgcn_mfma_f32_16x16x32_bf16(
                        af[mt][kk], bfv[nt][kk], acc[mt][nt], 0, 0, 0);
    }

    #pragma unroll
    for (int mt = 0; mt < MT; ++mt) {
        #pragma unroll
        for (int nt = 0; nt < NT; ++nt) {
            int col = col0 + wn * (BN / 2) + nt * 16 + l15;
            float bv = bias[col];
            #pragma unroll
            for (int r = 0; r < 4; ++r) {
                int row = row0 + wm * (BM / 2) + mt * 16 + quad * 4 + r;
                float v = acc[mt][nt][r] + bv;
                if (RESID) v += resid[(size_t)row * ldr + col];
                storec(&C[(size_t)row * ldc + col], v);
            }
        }
    }
}

// fused fp32 -> bf16 convert for 5 tensors; each block handles 1024 elems
__global__ void f2b_all(const float* __restrict__ s0, bf16* __restrict__ d0,
                        const float* __restrict__ s1, bf16* __restrict__ d1,
                        const float* __restrict__ s2, bf16* __restrict__ d2,
                        const float* __restrict__ s3, bf16* __restrict__ d3,
                        const float* __restrict__ s4, bf16* __restrict__ d4)
{
    int blk = blockIdx.x;
    const float* s; bf16* d; int base;
    if      (blk < 4096)  { s = s0; d = d0; base = blk; }
    else if (blk < 7168)  { s = s1; d = d1; base = blk - 4096; }
    else if (blk < 8192)  { s = s2; d = d2; base = blk - 7168; }
    else if (blk < 12288) { s = s3; d = d3; base = blk - 8192; }
    else                  { s = s4; d = d4; base = blk - 12288; }
    int i = base * 1024 + threadIdx.x * 4;
    float4 v = *(const float4*)&s[i];
    d[i + 0] = __float2bfloat16(v.x);
    d[i + 1] = __float2bfloat16(v.y);
    d[i + 2] = __float2bfloat16(v.z);
    d[i + 3] = __float2bfloat16(v.w);
}

// ---------------------------------------------------------------------------
// rope_all: block = (n-tile 64, h, b). Reads qkv[b,n][h*192 + d*3 + c] once via
// an LDS tile, writes RoPE'd q,k in [B,H,N,64] and V transposed in [B,H,64,N].
// ---------------------------------------------------------------------------
#define RS 196
__global__ __launch_bounds__(256)
void rope_all(const bf16* __restrict__ qkv, const float* __restrict__ enc,
              bf16* __restrict__ q, bf16* __restrict__ k, bf16* __restrict__ vt)
{
    __shared__ short raw[64 * RS];
    int n0 = blockIdx.x * 64, h = blockIdx.y, b = blockIdx.z;
    int t = threadIdx.x;
    const short* qg = (const short*)qkv;

    {
        int row = t >> 2, off = (t & 3) * 48;
        const short* src = qg + ((size_t)(b * N_ + n0 + row)) * 3072 + h * 192 + off;
        uint4 u[3];
        u[0] = ((const uint4*)src)[0];
        u[1] = ((const uint4*)src)[1];
        u[2] = ((const uint4*)src)[2];
        uint4 u2[3];
        u2[0] = ((const uint4*)src)[3];
        u2[1] = ((const uint4*)src)[4];
        u2[2] = ((const uint4*)src)[5];
        uint2* dst = (uint2*)&raw[row * RS + off];
        const uint2* p = (const uint2*)u;
        #pragma unroll
        for (int i = 0; i < 6; ++i) dst[i] = p[i];
        const uint2* p2 = (const uint2*)u2;
        #pragma unroll
        for (int i = 0; i < 6; ++i) dst[6 + i] = p2[i];
    }
    __syncthreads();

    size_t bh = (size_t)(b * H_ + h);
    {
        int d = t & 63, g0 = t >> 6;
        int dp = d ^ 1;
        float sgn = (d & 1) ? 1.0f : -1.0f;
        #pragma unroll
        for (int i = 0; i < 16; ++i) {
            int nl = g0 + 4 * i;
            const short* r = &raw[nl * RS];
            float qv = s2f(r[3 * d]),  kv = s2f(r[3 * d + 1]);
            float qp = s2f(r[3 * dp]), kp = s2f(r[3 * dp + 1]);
            size_t ei = ((size_t)(b * N_ + n0 + nl)) * HD_ + d;
            float c = enc[ei];
            float s = enc[(size_t)B_ * N_ * HD_ + ei];
            size_t o = (bh * N_ + n0 + nl) * HD_ + d;
            q[o] = __float2bfloat16(qv * c + sgn * qp * s);
            k[o] = __float2bfloat16(kv * c + sgn * kp * s);
        }
    }
    {
        int nl = t & 63, g0 = t >> 6;
        #pragma unroll
        for (int i = 0; i < 16; ++i) {
            int dt = g0 + 4 * i;
            vt[(bh * HD_ + dt) * N_ + n0 + nl] =
                *reinterpret_cast<bf16*>(&raw[nl * RS + 3 * dt + 2]);
        }
    }
}

// ---------------------------------------------------------------------------
// MFMA flash attention v7 (round-8/round-10 measured, restored): QBLK=128,
// K/V double-buffered LDS, ONE barrier per tile (16 total), T14 issue-early
// loads + T5 setprio. LDS 54KB, 2 blocks/CU.
// ---------------------------------------------------------------------------
__global__ __launch_bounds__(256, 2)
void fattn(const bf16* __restrict__ q, const bf16* __restrict__ k,
           const bf16* __restrict__ vt, bf16* __restrict__ ctx)
{
    const int i0 = blockIdx.x * 128;
    const int h = blockIdx.y, b = blockIdx.z;
    const int t = threadIdx.x;
    const int lane = t & 63;
    const int w = t >> 6;
    const int quad = lane >> 4, l15 = lane & 15;

    __shared__ alignas(16) short Ks[2][64 * 72];   // [buf][key][d]
    __shared__ alignas(16) short Vs[2][64 * 72];   // [buf][d][key]
    __shared__ alignas(16) short Ps[128 * 72];     // [q-row][key]

    const size_t bh = (size_t)(b * H_ + h) * N_;
    const size_t bhv = (size_t)(b * H_ + h) * HD_;
    const short* qg = (const short*)q;
    const short* kg = (const short*)k;
    const short* vg = (const short*)vt;

    // Q fragments (B-operand: n = q-row = l15, k = quad*8+j)
    shortx8 qf[2][2];
    #pragma unroll
    for (int rt = 0; rt < 2; ++rt) {
        const short* qrow = qg + (bh + i0 + w * 32 + rt * 16 + l15) * HD_;
        qf[rt][0] = *(const shortx8*)(qrow + quad * 8);
        qf[rt][1] = *(const shortx8*)(qrow + 32 + quad * 8);
    }

    floatx4 O[2][4];
    #pragma unroll
    for (int rt = 0; rt < 2; ++rt)
        #pragma unroll
        for (int dt = 0; dt < 4; ++dt) O[rt][dt] = (floatx4){0.f, 0.f, 0.f, 0.f};
    // per-lane partial row sums: q-row = w*32 + rt*16 + l15, keys {16kt + quad*4 + r}
    float lsum[2] = {0.f, 0.f};

    const int srow = t >> 2, soff = (t & 3) * 16;
    const short* kst = kg + (bh + srow) * HD_ + soff;     // + j0*HD_ per tile
    const short* vst = vg + (bhv + srow) * N_ + soff;     // + j0 per tile

    // prologue: load tile 0 into regs and write buf 0 (no barrier needed:
    // nothing reads before the first in-loop barrier)
    {
        uint4 a0 = ((const uint4*)kst)[0];
        uint4 a1 = ((const uint4*)kst)[1];
        uint4 b0 = ((const uint4*)vst)[0];
        uint4 b1 = ((const uint4*)vst)[1];
        *(uint4*)&Ks[0][srow * 72 + soff]     = a0;
        *(uint4*)&Ks[0][srow * 72 + soff + 8] = a1;
        *(uint4*)&Vs[0][srow * 72 + soff]     = b0;
        *(uint4*)&Vs[0][srow * 72 + soff + 8] = b1;
    }

    uint4 ka0, ka1, va0, va1;
    for (int it = 0; it < N_ / 64; ++it) {
        const int cur = it & 1;
        __syncthreads();   // buf[cur] writes drained; buf[cur^1] readers done

        // issue next tile's loads: fly over the whole compute phase
        if (it + 1 < N_ / 64) {
            const int j1 = (it + 1) * 64;
            const short* kn = kst + (size_t)j1 * HD_;
            const short* vn = vst + j1;
            ka0 = ((const uint4*)kn)[0];
            ka1 = ((const uint4*)kn)[1];
            va0 = ((const uint4*)vn)[0];
            va1 = ((const uint4*)vn)[1];
        }

        // S^T = K Q^T : A = K-frag (m=key), B = Q-frag (n=q-row)
        // C-layout: col(l15) = q-row, row(quad*4+r) = key
        floatx4 ST[4][2];
        __builtin_amdgcn_s_setprio(1);
        #pragma unroll
        for (int kt = 0; kt < 4; ++kt) {
            shortx8 a0 = *(const shortx8*)&Ks[cur][(kt * 16 + l15) * 72 + quad * 8];
            shortx8 a1 = *(const shortx8*)&Ks[cur][(kt * 16 + l15) * 72 + 32 + quad * 8];
            #pragma unroll
            for (int rt = 0; rt < 2; ++rt) {
                floatx4 c = (floatx4){0.f, 0.f, 0.f, 0.f};
                c = __builtin_amdgcn_mfma_f32_16x16x32_bf16(a0, qf[rt][0], c, 0, 0, 0);
                c = __builtin_amdgcn_mfma_f32_16x16x32_bf16(a1, qf[rt][1], c, 0, 0, 0);
                ST[kt][rt] = c;
            }
        }
        __builtin_amdgcn_s_setprio(0);

        // exp + per-lane sums + packed b64 P-writes (4 consecutive keys/lane)
        #pragma unroll
        for (int kt = 0; kt < 4; ++kt)
            #pragma unroll
            for (int rt = 0; rt < 2; ++rt) {
                unsigned short pk[4];
                #pragma unroll
                for (int r = 0; r < 4; ++r) {
                    float e = __expf(ST[kt][rt][r] * 0.125f);
                    lsum[rt] += e;
                    pk[r] = bf_bits(e);
                }
                *(uint2*)&Ps[(w * 32 + rt * 16 + l15) * 72 + kt * 16 + quad * 4] =
                    *(const uint2*)pk;
            }

        // PV (same-wave Ps write->read; per-wave LDS ordering)
        shortx8 pa[2][2];
        #pragma unroll
        for (int rt = 0; rt < 2; ++rt) {
            pa[rt][0] = *(const shortx8*)&Ps[(w * 32 + rt * 16 + l15) * 72 + quad * 8];
            pa[rt][1] = *(const shortx8*)&Ps[(w * 32 + rt * 16 + l15) * 72 + 32 + quad * 8];
        }
        __builtin_amdgcn_s_setprio(1);
        #pragma unroll
        for (int dt = 0; dt < 4; ++dt) {
            shortx8 vb0 = *(const shortx8*)&Vs[cur][(dt * 16 + l15) * 72 + quad * 8];
            shortx8 vb1 = *(const shortx8*)&Vs[cur][(dt * 16 + l15) * 72 + 32 + quad * 8];
            #pragma unroll
            for (int rt = 0; rt < 2; ++rt) {
                O[rt][dt] = __builtin_amdgcn_mfma_f32_16x16x32_bf16(pa[rt][0], vb0, O[rt][dt], 0, 0, 0);
                O[rt][dt] = __builtin_amdgcn_mfma_f32_16x16x32_bf16(pa[rt][1], vb1, O[rt][dt], 0, 0, 0);
            }
        }
        __builtin_amdgcn_s_setprio(0);

        // write staged regs into the other buffer (readers passed the barrier)
        if (it + 1 < N_ / 64) {
            *(uint4*)&Ks[cur ^ 1][srow * 72 + soff]     = ka0;
            *(uint4*)&Ks[cur ^ 1][srow * 72 + soff + 8] = ka1;
            *(uint4*)&Vs[cur ^ 1][srow * 72 + soff]     = va0;
            *(uint4*)&Vs[cur ^ 1][srow * 72 + soff + 8] = va1;
        }
    }

    // epilogue: complete row sums (reduce across quads -> full sum at q-row=l15),
    // redistribute to O's row indexing (q-row = quad*4 + r) via shfl, store.
    #pragma unroll
    for (int rt = 0; rt < 2; ++rt) {
        float rs = lsum[rt];
        rs += __shfl_xor(rs, 16);
        rs += __shfl_xor(rs, 32);
        #pragma unroll
        for (int r = 0; r < 4; ++r) {
            float inv = 1.0f / __shfl(rs, quad * 4 + r);
            int row = i0 + w * 32 + rt * 16 + quad * 4 + r;
            #pragma unroll
            for (int dt = 0; dt < 4; ++dt)
                ctx[((size_t)(b * N_ + row)) * D_ + h * HD_ + dt * 16 + l15] =
                    __float2bfloat16(O[rt][dt][r] * inv);
        }
    }
}

// LayerNorm over 2048 cols + exact GELU, in place on bf16. One block per row.
// Vectorized b128 loads/stores (8 bf16/thread) + shfl-based reduction.
__global__ void ln_gelu(bf16* __restrict__ hbuf, const float* __restrict__ g,
                        const float* __restrict__ beta)
{
    int row = blockIdx.x;
    int t = threadIdx.x;
    short* hr = (short*)hbuf + (size_t)row * 2048;

    shortx8 v = *(const shortx8*)&hr[t * 8];
    float vals[8];
    float s = 0.f, s2 = 0.f;
    #pragma unroll
    for (int l = 0; l < 8; ++l) {
        float x = s2f(v[l]);
        vals[l] = x; s += x; s2 += x * x;
    }
    // wave reduce (64 lanes), then 4 wave partials via LDS
    #pragma unroll
    for (int off = 32; off >= 1; off >>= 1) {
        s  += __shfl_xor(s,  off);
        s2 += __shfl_xor(s2, off);
    }
    __shared__ float ws_[4], ws2_[4];
    if ((t & 63) == 0) { ws_[t >> 6] = s; ws2_[t >> 6] = s2; }
    __syncthreads();
    float S  = ws_[0] + ws_[1] + ws_[2] + ws_[3];
    float S2 = ws2_[0] + ws2_[1] + ws2_[2] + ws2_[3];

    float mu  = S * (1.0f / 2048.0f);
    float var = S2 * (1.0f / 2048.0f) - mu * mu;
    float rstd = rsqrtf(var + 1e-5f);

    float4 g0 = *(const float4*)&g[t * 8];
    float4 g1 = *(const float4*)&g[t * 8 + 4];
    float4 b0 = *(const float4*)&beta[t * 8];
    float4 b1 = *(const float4*)&beta[t * 8 + 4];
    float gv[8] = {g0.x, g0.y, g0.z, g0.w, g1.x, g1.y, g1.z, g1.w};
    float bv[8] = {b0.x, b0.y, b0.z, b0.w, b1.x, b1.y, b1.z, b1.w};

    shortx8 o;
    #pragma unroll
    for (int l = 0; l < 8; ++l) {
        float xn = (vals[l] - mu) * rstd * gv[l] + bv[l];
        float ge = 0.5f * xn * (1.0f + erff(xn * 0.70710678118654752f));
        o[l] = (short)bf_bits(ge);
    }
    *(shortx8*)&hr[t * 8] = o;
}

extern "C" void kernel_launch(void* const* d_in, const int* in_sizes, int n_in,
                              void* d_out, int out_size, void* d_ws, size_t ws_size,
                              hipStream_t stream)
{
    const float* x      = (const float*)d_in[0];
    const float* enc    = (const float*)d_in[1];
    const float* Wqkv_w = (const float*)d_in[2];
    const float* Wqkv_b = (const float*)d_in[3];
    const float* out_w  = (const float*)d_in[4];
    const float* out_b  = (const float*)d_in[5];
    const float* ffn1_w = (const float*)d_in[6];
    const float* ffn1_b = (const float*)d_in[7];
    const float* ln_g   = (const float*)d_in[8];
    const float* ln_b   = (const float*)d_in[9];
    const float* ffn2_w = (const float*)d_in[10];
    const float* ffn2_b = (const float*)d_in[11];
    float* out = (float*)d_out;

    float* ws = (float*)d_ws;
    bf16* qkv16 = (bf16*)ws;
    bf16* ctx16 = (bf16*)ws;
    bf16* h16   = (bf16*)(ws + 2097152);
    bf16* q16   = (bf16*)(ws + 6291456);
    bf16* k16   = q16 + 2097152;
    bf16* vt16  = k16 + 2097152;
    bf16* msg16 = (bf16*)(ws + 6291456);    // overlays q16 after fattn
    bf16* x16   = (bf16*)(ws + 12582912);
    bf16* wq16  = (bf16*)(ws + 14680064);
    bf16* wo16  = wq16 + 3145728;
    bf16* wf1   = wo16 + 1048576;
    bf16* wf2   = wf1 + 4194304;

    // 0. fused converts (x, Wqkv, out_w, ffn1_w, ffn2_w)
    f2b_all<<<14336, 256, 0, stream>>>(x, x16, Wqkv_w, wq16, out_w, wo16,
                                       ffn1_w, wf1, ffn2_w, wf2);

    // 1. qkv = x @ Wqkv^T + b  [4096, 3072] bf16
    //    BN=192/BK=64: grid 16x32 = 512 = exactly 2 blocks/CU (LDS 80KB),
    //    no tail, 3x MFMA per barrier vs the old BK=32 config.
    dim3 g1(3072 / 192, 4096 / 128);
    mgemm<bf16, false, false, 128, 192, 64><<<g1, 256, 0, stream>>>(
        x16, 1024, nullptr, 0, 0, wq16, 1024, Wqkv_b, nullptr, 0,
        qkv16, 3072, 4096, 3072, 1024);

    // 2. RoPE + split + V-transpose
    dim3 gr(16, 16, 4);
    rope_all<<<gr, 256, 0, stream>>>(qkv16, enc, q16, k16, vt16);

    // 3. MFMA flash attention -> ctx bf16 [4096, 1024] (grid 512, QBLK=128)
    dim3 ga(N_ / 128, H_, B_);
    fattn<<<ga, 256, 0, stream>>>(q16, k16, vt16, ctx16);

    // 4. message = ctx @ out_w^T + out_b -> msg16 (grid 512 = 2/CU: BK=64)
    dim3 g2(1024 / 64, 4096 / 128);
    mgemm<bf16, false, false, 128, 64, 64><<<g2, 256, 0, stream>>>(
        ctx16, 1024, nullptr, 0, 0, wo16, 1024, out_b, nullptr, 0,
        msg16, 1024, 4096, 1024, 1024);

    // 5. h = [x | message] @ ffn1_w^T + ffn1_b  (grid 512 = 2/CU: BK=64)
    dim3 g3(2048 / 128, 4096 / 128);
    mgemm<bf16, false, true, 128, 128, 64><<<g3, 256, 0, stream>>>(
        x16, 1024, msg16, 1024, 1024, wf1, 2048, ffn1_b, nullptr, 0,
        h16, 2048, 4096, 2048, 2048);

    // 6. LayerNorm + exact GELU in place (bf16)
    ln_gelu<<<4096, 256, 0, stream>>>(h16, ln_g, ln_b);

    // 7. out = x + h @ ffn2_w^T + ffn2_b  (grid 512 = 2/CU: BK=64)
    dim3 g4(1024 / 64, 4096 / 128);
    mgemm<float, true, false, 128, 64, 64><<<g4, 256, 0, stream>>>(
        h16, 2048, nullptr, 0, 0, wf2, 2048, ffn2_b, x, 1024,
        out, 1024, 4096, 1024, 2048);
}